// Round 11
// baseline (123.038 us; speedup 1.0000x reference)
//
#include <hip/hip_runtime.h>

// KMeans soft-assignment via bf16 hi/lo split MFMA (3 passes), fused softmax.
// logits = (2*x.c - ||c||^2)/T, T=0.1; ||x||^2 cancels in softmax.
// R11: 256-thr blocks, BM=64, mfma_32x32x16, BK=16 double-buffered B via
// global_load_lds (zero staging regs). LDS ~67 KB + <=256 regs -> 2 blocks/CU
// so barrier drains of one block hide under the other block's compute (m114).
// x: [32768,256] f32, c: [512,256] f32, out: [32768,512] f32
#define NROWS 32768
#define KC 512
#define DDIM 256
#define BM 64
#define BK 16
#define KCH (DDIM / BK)        // 16 k-chunks
#define CHUNK_USH (KC * BK)    // 8192 ushorts = 16 KB per chunk table

typedef __attribute__((ext_vector_type(8)))  short bf16x8;
typedef __attribute__((ext_vector_type(16))) float f32x16;

union U8 { unsigned short u[8]; bf16x8 v; };

__device__ __forceinline__ unsigned short f2bf(float f) {   // RNE f32->bf16
    union { float f; unsigned int u; } a; a.f = f;
    unsigned int r = a.u + 0x7fffu + ((a.u >> 16) & 1u);
    return (unsigned short)(r >> 16);
}
__device__ __forceinline__ float bf2f(unsigned short h) {
    union { unsigned int u; float f; } a; a.u = ((unsigned int)h) << 16;
    return a.f;
}
// async global->LDS, 16B/lane; LDS dst = wave-uniform base + lane*16
__device__ __forceinline__ void ld16(const void* g, void* l) {
    __builtin_amdgcn_global_load_lds(
        (const __attribute__((address_space(1))) unsigned int*)g,
        (__attribute__((address_space(3))) unsigned int*)l, 16, 0, 0);
}

// ---- prep: c -> chunk-major bf16 hi/lo, bank-swizzled for 32x32 frags ----
// octet (col n, half h) of chunk ks at ushort offset:
//   ks*CHUNK_USH + (n>>5)*512 + (((2*(n&31)+h) ^ (((n&31)>>2)&1)))*8
__global__ __launch_bounds__(64) void prep_c(const float* __restrict__ c,
                                             unsigned short* __restrict__ bhi,
                                             unsigned short* __restrict__ blo,
                                             float* __restrict__ csq10) {
    const int n = blockIdx.x, lane = threadIdx.x;
    const int d0 = lane * 4;
    float4 v = ((const float4*)(c + (size_t)n * DDIM))[lane];
    float vv[4] = {v.x, v.y, v.z, v.w};
    unsigned short hh[4], ll[4];
    float ssq = 0.f;
    #pragma unroll
    for (int i = 0; i < 4; ++i) {
        ssq += vv[i] * vv[i];
        hh[i] = f2bf(vv[i]);
        ll[i] = f2bf(vv[i] - bf2f(hh[i]));
    }
    #pragma unroll
    for (int off = 32; off; off >>= 1) ssq += __shfl_xor(ssq, off);
    if (lane == 0) csq10[n] = 10.f * ssq;
    const int ks = d0 >> 4;                 // 0..15
    const int h  = (d0 >> 3) & 1;           // k-octet half
    const int j0 = d0 & 7;                  // 0 or 4
    const int c5 = n & 31, tile = n >> 5;
    const int p  = (2 * c5 + h) ^ ((c5 >> 2) & 1);
    const size_t dst = (size_t)ks * CHUNK_USH + tile * 512 + p * 8 + j0;
    *(ushort4*)(bhi + dst) = make_ushort4(hh[0], hh[1], hh[2], hh[3]);
    *(ushort4*)(blo + dst) = make_ushort4(ll[0], ll[1], ll[2], ll[3]);
}

// ---- main: 512 blocks x 256 threads (4 waves = 2 M-groups x 2 N-halves) ----
// wave (wm,wn): rows wm*32..+31 (32x32 M), cols wn*256 (8 tiles of 32)
union SmemU {
    struct { unsigned short Bh[2][CHUNK_USH], Bl[2][CHUNK_USH]; } k;  // 64 KB
    float lbuf[16 * 516];                                             // 33 KB
};

__global__ __launch_bounds__(256, 2) void kmeans_mfma(
    const float* __restrict__ x, const unsigned short* __restrict__ bhi,
    const unsigned short* __restrict__ blo, const float* __restrict__ csq10,
    float* __restrict__ out) {
    __shared__ __align__(16) SmemU sm;
    __shared__ float  red0[2][BM], red1[2][BM];   // 1 KB
    __shared__ float2 MI[BM];                     // 0.5 KB

    const int tid  = threadIdx.x;
    const int w    = tid >> 6, lane = tid & 63;
    const int wm   = w >> 1, wn = w & 1;
    const int c5   = lane & 31, h = lane >> 5;
    const int row0 = blockIdx.x * BM;

    f32x16 acc[8];
    #pragma unroll
    for (int t = 0; t < 8; ++t)
        #pragma unroll
        for (int r = 0; r < 16; ++r) acc[t][r] = 0.f;

    // A: lane owns row (row0 + wm*32 + c5), k-octet h*8 of each 16-k chunk
    const float* xrow = x + (size_t)(row0 + wm * 32 + c5) * DDIM + h * 8;
    // B fragment offset within a staged chunk (swizzled octet)
    const int bRd    = ((2 * c5 + h) ^ ((c5 >> 2) & 1)) * 8;
    const int dmaOff = (w * 4) * 512;   // wave's 4 x 1KB DMA segments

    // ---- prologue: DMA chunk 0 -> buf 0; A(0) raw ----
    #pragma unroll
    for (int j = 0; j < 4; ++j) {
        const int o = dmaOff + j * 512;
        ld16(bhi + o + lane * 8, &sm.k.Bh[0][o]);
        ld16(blo + o + lane * 8, &sm.k.Bl[0][o]);
    }
    float4 a0 = *(const float4*)xrow;
    float4 a1 = *(const float4*)(xrow + 4);
    __syncthreads();

    for (int ks = 0; ks < KCH; ++ks) {
        const int pp = ks & 1;
        float4 n0, n1;
        if (ks < KCH - 1) {
            const size_t cb = (size_t)(ks + 1) * CHUNK_USH;
            #pragma unroll
            for (int j = 0; j < 4; ++j) {
                const int o = dmaOff + j * 512;
                ld16(bhi + cb + o + lane * 8, &sm.k.Bh[1 - pp][o]);
                ld16(blo + cb + o + lane * 8, &sm.k.Bl[1 - pp][o]);
            }
            n0 = *(const float4*)(xrow + (ks + 1) * BK);
            n1 = *(const float4*)(xrow + (ks + 1) * BK + 4);
        }
        // convert A to hi/lo fragments
        bf16x8 ah, al;
        {
            float v8[8] = {a0.x, a0.y, a0.z, a0.w, a1.x, a1.y, a1.z, a1.w};
            U8 H, L;
            #pragma unroll
            for (int i = 0; i < 8; ++i) {
                H.u[i] = f2bf(v8[i]);
                L.u[i] = f2bf(v8[i] - bf2f(H.u[i]));
            }
            ah = H.v; al = L.v;
        }
        // MFMA over staged buffer pp: 8 col-tiles of 32
        #pragma unroll
        for (int t = 0; t < 8; ++t) {
            const int bo = (wn * 8 + t) * 512 + bRd;
            bf16x8 bh = *(const bf16x8*)&sm.k.Bh[pp][bo];
            bf16x8 bl = *(const bf16x8*)&sm.k.Bl[pp][bo];
            acc[t] = __builtin_amdgcn_mfma_f32_32x32x16_bf16(ah, bh, acc[t], 0, 0, 0);
            acc[t] = __builtin_amdgcn_mfma_f32_32x32x16_bf16(ah, bl, acc[t], 0, 0, 0);
            acc[t] = __builtin_amdgcn_mfma_f32_32x32x16_bf16(al, bh, acc[t], 0, 0, 0);
        }
        a0 = n0; a1 = n1;
        __syncthreads();   // next-chunk DMA drained; all waves done with buf pp
    }

    // ---- softmax stats; C/D: col = c5 (tile*32+c5), row = (r&3)+8*(r>>2)+4h
    float csqv[8];
    #pragma unroll
    for (int t = 0; t < 8; ++t) csqv[t] = csq10[wn * 256 + t * 32 + c5];

    #pragma unroll
    for (int r = 0; r < 16; ++r) {
        float pm = -1e30f;
        #pragma unroll
        for (int t = 0; t < 8; ++t) pm = fmaxf(pm, 20.f * acc[t][r] - csqv[t]);
        #pragma unroll
        for (int off = 1; off < 32; off <<= 1) pm = fmaxf(pm, __shfl_xor(pm, off));
        if (c5 == 0) red0[wn][wm * 32 + (r & 3) + 8 * (r >> 2) + 4 * h] = pm;
    }
    __syncthreads();
    #pragma unroll
    for (int r = 0; r < 16; ++r) {
        const int row = wm * 32 + (r & 3) + 8 * (r >> 2) + 4 * h;
        const float Mf = fmaxf(red0[0][row], red0[1][row]);   // LDS broadcast
        float ps = 0.f;
        #pragma unroll
        for (int t = 0; t < 8; ++t) ps += __expf(20.f * acc[t][r] - csqv[t] - Mf);
        #pragma unroll
        for (int off = 1; off < 32; off <<= 1) ps += __shfl_xor(ps, off);
        if (c5 == 0) red1[wn][row] = ps;
    }
    __syncthreads();
    if (tid < BM) {
        const float Mf = fmaxf(red0[0][tid], red0[1][tid]);
        const float Sf = red1[0][tid] + red1[1][tid];
        MI[tid] = make_float2(Mf, 1.f / Sf);
    }
    __syncthreads();

    // ---- transpose epilogue: 4 passes of 16 rows through lbuf ----
    #pragma unroll
    for (int p = 0; p < 4; ++p) {
        if (wm == (p >> 1)) {
            #pragma unroll
            for (int i = 0; i < 8; ++i) {
                const int    rr  = (p & 1) * 8 + i;                 // acc reg
                const int    lr  = (i & 3) + 8 * (i >> 2) + 4 * h;  // 0..15
                const float2 mi  = MI[p * 16 + lr];
                #pragma unroll
                for (int t = 0; t < 8; ++t)
                    sm.lbuf[lr * 516 + wn * 256 + t * 32 + c5] =
                        __expf(20.f * acc[t][rr] - csqv[t] - mi.x) * mi.y;
            }
        }
        __syncthreads();
        #pragma unroll
        for (int j = 0; j < 8; ++j) {
            const int f    = j * 256 + tid;     // 0..2047 float4 slots
            const int lrow = f >> 7;            // 0..15
            const int c4   = f & 127;
            float4    v    = *(const float4*)&sm.lbuf[lrow * 516 + c4 * 4];
            *(float4*)(out + (size_t)(row0 + p * 16 + lrow) * KC + c4 * 4) = v;
        }
        __syncthreads();
    }
}

extern "C" void kernel_launch(void* const* d_in, const int* in_sizes, int n_in,
                              void* d_out, int out_size, void* d_ws, size_t ws_size,
                              hipStream_t stream) {
    const float* x   = (const float*)d_in[0];
    const float* c   = (const float*)d_in[1];
    float*       out = (float*)d_out;

    unsigned short* bhi   = (unsigned short*)d_ws;                 // 256 KB
    unsigned short* blo   = bhi + (size_t)KCH * CHUNK_USH;         // 256 KB
    float*          csq10 = (float*)(blo + (size_t)KCH * CHUNK_USH);  // 2 KB

    prep_c<<<KC, 64, 0, stream>>>(c, bhi, blo, csq10);
    kmeans_mfma<<<NROWS / BM, 256, 0, stream>>>(x, bhi, blo, csq10, out);
}